// Round 4
// baseline (632.241 us; speedup 1.0000x reference)
//
#include <hip/hip_runtime.h>
#include <hip/hip_bf16.h>
#include <stdint.h>

// Fused Kronecker-factorized linear via bf16-split MFMA (3-product fp32 emulation):
//   out[b, 128*gp + g] = sum_{r,f} x[b, 128*r + f] * w0[f][g] * w1[r][gp]
//   (per batch: Out = W1^T * X * W0, all 128x128)
//
// v2 "stream-T" restructure (round-3 counters: all pipes ~22% => latency-bound,
// 2 blocks/CU from 64KB LDS was the cause):
//  - No X staging: phase-1 A-fragments read fp32 straight from global (all 4
//    waves share the same 16KB X window per chunk -> L1/L2 absorbs the 4x).
//  - T streamed through a single 16KB LDS chunk (32 rows x 128 cols, bf16
//    hi/lo), produce->barrier->consume (K=32 MFMA step)->barrier, 4 chunks.
//  - Persistent O accumulators: wave w owns O rows [32w, 32w+32) (64 VGPRs).
//  - 16KB LDS + launch_bounds(256,3) -> 3 blocks/CU = 12 waves/CU (vs 8).
//
// Fragment convention (shared by prep + main; identical to the round-3 kernel
// that passed): lane l supplies operand elems j=0..7 at k=(l>>4)*8+j;
// A row / B col = l&15. A/B use the same convention so the true HW k-slot
// permutation cancels. C/D: col=l&15, row=(l>>4)*4+reg (HW-verified m89/m91).
//
// T-LDS layout: Th/Tl[128 g][32 r_local] bf16 (8KB each). 16B-granule XOR
// swizzle: granule' = granule ^ (g&3). Write side (b64, tiles of 4 r) and
// read side (b128, 8 r) both hit 1 lane per 16B slot per 128B bank-row ->
// per-instruction LDS optimum.

typedef unsigned short u16;
typedef __attribute__((ext_vector_type(8))) short short8;
typedef __attribute__((ext_vector_type(4))) float float4v;

__device__ __forceinline__ uint32_t pk_bf16(float a, float b) {
    // packs bf16(a) in low 16, bf16(b) in high 16 (RNE)
    __hip_bfloat162 h = __float22bfloat162_rn(make_float2(a, b));
    uint32_t u;
    __builtin_memcpy(&u, &h, 4);
    return u;
}

union S8U { short8 s; uint32_t u[4]; };

// split 8 consecutive fp32 into bf16 hi/lo short8 fragments
__device__ __forceinline__ void split8(const float v[8], short8& hi, short8& lo) {
    S8U H, L;
    #pragma unroll
    for (int p = 0; p < 4; ++p) {
        const uint32_t h = pk_bf16(v[2 * p], v[2 * p + 1]);
        H.u[p] = h;
        const float r0 = v[2 * p]     - __uint_as_float(h << 16);
        const float r1 = v[2 * p + 1] - __uint_as_float(h & 0xFFFF0000u);
        L.u[p] = pk_bf16(r0, r1);
    }
    hi = H.s;
    lo = L.s;
}

// ---------------- Kernel 1: weight fragment prep (unchanged, verified) ----
// d_ws layout (u16 units): [0]=W0hi, [16384]=W0lo, [32768]=W1hi, [49152]=W1lo.
// Fragment linear index r = ((ktile*8 + tile)*64 + lane)*8 + j.
// W0 (phase-1 B): value = w0[k][n], n = tile*16 + (l&15)
// W1 (phase-2 A): value = w1[k][m], m = tile*16 + (l&15)   (A = W1^T)
// both with k = ktile*32 + (l>>4)*8 + j.
__global__ void prep_weights(const float* __restrict__ w0,
                             const float* __restrict__ w1,
                             u16* __restrict__ wsp) {
    const int tid = blockIdx.x * 256 + threadIdx.x;  // 0..32767
    const int m  = tid >> 14;                        // 0: w0, 1: w1
    const int r  = tid & 16383;
    const int fi = r >> 9;        // 0..31
    const int l  = (r >> 3) & 63;
    const int j  = r & 7;
    const int ktile = fi >> 3, tile = fi & 7;
    const int k = ktile * 32 + (l >> 4) * 8 + j;
    const int c = tile * 16 + (l & 15);
    const float v = (m ? w1 : w0)[k * 128 + c];

    const uint32_t hu = pk_bf16(v, 0.0f);
    const u16 hb = (u16)(hu & 0xFFFF);
    const float hf = __uint_as_float(hu << 16);
    const u16 lb = (u16)(pk_bf16(v - hf, 0.0f) & 0xFFFF);

    u16* base = wsp + m * 32768;
    base[r] = hb;
    base[16384 + r] = lb;
}

// ---------------- Kernel 2: stream-T fused sandwich ----------------
__global__ __launch_bounds__(256, 3) void faclin_stream(
    const float* __restrict__ x,     // (B, 16384) fp32
    const u16* __restrict__ wsp,     // prepped weight frags
    float* __restrict__ out)         // (B, 16384) fp32
{
    __shared__ alignas(16) u16 Th[4096];  // T chunk hi: [g][r_local] swizzled, 8KB
    __shared__ alignas(16) u16 Tl[4096];  // T chunk lo, 8KB

    const int b = blockIdx.x;
    const int t = threadIdx.x;
    const int l = t & 63, w = t >> 6;
    const int l15 = l & 15, lg = l >> 4;
    const float* __restrict__ xb = x + (size_t)b * 16384;
    float* __restrict__ ob = out + (size_t)b * 16384;

    const u16* __restrict__ W0h = wsp;
    const u16* __restrict__ W0l = wsp + 16384;
    const u16* __restrict__ W1h = wsp + 32768;
    const u16* __restrict__ W1l = wsp + 49152;

    // Persistent phase-2 accumulators: O rows [32w, 32w+32), all 128 cols.
    float4v acc2[2][8];
    #pragma unroll
    for (int i = 0; i < 2; ++i)
        #pragma unroll
        for (int j = 0; j < 8; ++j) acc2[i][j] = {0.f, 0.f, 0.f, 0.f};

    for (int c = 0; c < 4; ++c) {  // T row-chunk r in [32c, 32c+32)
        // ---- Produce: T[32c.., 32w + nt*16 ..] = X * W0 (full f contraction)
        float4v accP[2][2];
        #pragma unroll
        for (int i = 0; i < 2; ++i)
            #pragma unroll
            for (int j = 0; j < 2; ++j) accP[i][j] = {0.f, 0.f, 0.f, 0.f};

        #pragma unroll
        for (int kt = 0; kt < 4; ++kt) {
            short8 ah[2], al[2], bh[2], bl[2];
            #pragma unroll
            for (int mt = 0; mt < 2; ++mt) {
                // A = X rows (direct global, fp32 -> hi/lo in registers)
                const float* p = xb + (size_t)(32 * c + mt * 16 + l15) * 128
                               + kt * 32 + lg * 8;
                float v[8];
                *(float4*)&v[0] = *(const float4*)p;
                *(float4*)&v[4] = *(const float4*)(p + 4);
                split8(v, ah[mt], al[mt]);
            }
            #pragma unroll
            for (int nt = 0; nt < 2; ++nt) {
                const int fi  = kt * 8 + 2 * w + nt;  // g-tile = 2w+nt
                const int off = (fi * 64 + l) * 8;
                bh[nt] = *(const short8*)&W0h[off];
                bl[nt] = *(const short8*)&W0l[off];
            }
            #pragma unroll
            for (int mt = 0; mt < 2; ++mt)
                #pragma unroll
                for (int nt = 0; nt < 2; ++nt) {
                    accP[mt][nt] = __builtin_amdgcn_mfma_f32_16x16x32_bf16(al[mt], bh[nt], accP[mt][nt], 0, 0, 0);
                    accP[mt][nt] = __builtin_amdgcn_mfma_f32_16x16x32_bf16(ah[mt], bl[nt], accP[mt][nt], 0, 0, 0);
                    accP[mt][nt] = __builtin_amdgcn_mfma_f32_16x16x32_bf16(ah[mt], bh[nt], accP[mt][nt], 0, 0, 0);
                }
        }

        // ---- Write T chunk to LDS (bf16 hi/lo, col-major [g][r_local], swizzled)
        // acc reg q: r_local = mt*16 + lg*4 + q, g = 32w + nt*16 + l15.
        #pragma unroll
        for (int mt = 0; mt < 2; ++mt)
            #pragma unroll
            for (int nt = 0; nt < 2; ++nt) {
                const int g = 32 * w + nt * 16 + l15;
                const int o = mt * 32 + lg * 8;               // byte off in 64B row
                const int gran = ((o >> 4) ^ (g & 3));
                const int idx = g * 32 + gran * 8 + ((o & 15) >> 1);  // u16 index
                const float4v a = accP[mt][nt];
                const uint32_t h01 = pk_bf16(a[0], a[1]);
                const uint32_t h23 = pk_bf16(a[2], a[3]);
                const float f0 = __uint_as_float(h01 << 16);
                const float f1 = __uint_as_float(h01 & 0xFFFF0000u);
                const float f2 = __uint_as_float(h23 << 16);
                const float f3 = __uint_as_float(h23 & 0xFFFF0000u);
                const uint32_t l01 = pk_bf16(a[0] - f0, a[1] - f1);
                const uint32_t l23 = pk_bf16(a[2] - f2, a[3] - f3);
                *(uint64_t*)&Th[idx] = (uint64_t)h01 | ((uint64_t)h23 << 32);
                *(uint64_t*)&Tl[idx] = (uint64_t)l01 | ((uint64_t)l23 << 32);
            }
        __syncthreads();

        // ---- Consume: O[32w..][:] += W1^T[.., k-chunk] * T-chunk (K=32 step)
        short8 a2h[2], a2l[2];
        #pragma unroll
        for (int mt = 0; mt < 2; ++mt) {
            const int fi  = c * 8 + 2 * w + mt;  // ktile=c, gp-tile = 2w+mt
            const int off = (fi * 64 + l) * 8;
            a2h[mt] = *(const short8*)&W1h[off];
            a2l[mt] = *(const short8*)&W1l[off];
        }
        #pragma unroll
        for (int nt = 0; nt < 8; ++nt) {
            const int g = nt * 16 + l15;
            const int gran = lg ^ (g & 3);
            const int idx = g * 32 + gran * 8;   // b128: r_local = lg*8 .. +7
            const short8 bh = *(const short8*)&Th[idx];
            const short8 bl = *(const short8*)&Tl[idx];
            #pragma unroll
            for (int mt = 0; mt < 2; ++mt) {
                acc2[mt][nt] = __builtin_amdgcn_mfma_f32_16x16x32_bf16(a2l[mt], bh, acc2[mt][nt], 0, 0, 0);
                acc2[mt][nt] = __builtin_amdgcn_mfma_f32_16x16x32_bf16(a2h[mt], bl, acc2[mt][nt], 0, 0, 0);
                acc2[mt][nt] = __builtin_amdgcn_mfma_f32_16x16x32_bf16(a2h[mt], bh, acc2[mt][nt], 0, 0, 0);
            }
        }
        __syncthreads();  // T chunk fully consumed before next produce
    }

    // ---- Store O. C/D: row = lg*4 + q, col = l15 per 16x16 tile.
    #pragma unroll
    for (int mt = 0; mt < 2; ++mt)
        #pragma unroll
        for (int nt = 0; nt < 8; ++nt)
            #pragma unroll
            for (int q = 0; q < 4; ++q) {
                const int orow = 32 * w + mt * 16 + lg * 4 + q;
                const int ocol = nt * 16 + l15;
                ob[(size_t)orow * 128 + ocol] = acc2[mt][nt][q];
            }
}

extern "C" void kernel_launch(void* const* d_in, const int* in_sizes, int n_in,
                              void* d_out, int out_size, void* d_ws, size_t ws_size,
                              hipStream_t stream) {
    const float* x  = (const float*)d_in[0];
    const float* w0 = (const float*)d_in[1];
    const float* w1 = (const float*)d_in[2];
    float* out = (float*)d_out;
    u16* wsp = (u16*)d_ws;  // 128 KB of scratch used

    const int B = in_sizes[0] >> 14;  // 4096

    prep_weights<<<128, 256, 0, stream>>>(w0, w1, wsp);
    faclin_stream<<<B, 256, 0, stream>>>(x, (const u16*)wsp, out);
}

// Round 9
// 592.154 us; speedup vs baseline: 1.0677x; 1.0677x over previous
//
#include <hip/hip_runtime.h>
#include <hip/hip_bf16.h>
#include <stdint.h>

// Fused Kronecker-factorized linear via bf16-split MFMA (3-product fp32 emulation):
//   out[b, 128*gp + g] = sum_{r,f} x[b, 128*r + f] * w0[f][g] * w1[r][gp]
//   (per batch: Out = W1^T * X * W0, all 128x128)
//
// v3 "chunked stage + stream-T" (post-mortem of v2's regression: direct-global
// A-fragment gathers serialized the produce phase and thrashed L1; v1's bulk
// coalesced staging was right, it just had 2 blocks/CU):
//  - Key structure: T rows [32c,32c+32) need only X rows [32c,32c+32) (phase-1
//    contracts within-row). Stream both X and T through small LDS chunks.
//  - Per chunk: bulk-coalesced float4 load of 16KB X-chunk (all 4 loads in
//    flight before any split) -> bf16 hi/lo in LDS -> produce T-chunk (MFMA)
//    -> T-chunk hi/lo in LDS (80B-padded rows) -> consume K=32 step into
//    persistent O accumulators.
//  - LDS 36KB, launch_bounds(256,4) -> 4 blocks/CU = 16 waves/CU; 3 barriers
//    per chunk are cross-filled by the other 3 resident blocks.
//
// Bank math (per-instruction, 32 banks x 4B, floor = bytes/128B per cycle):
//  - Xh/Xl [32 r][128 f] bf16, granule(16B) XOR: gran' = gran ^ (r&15).
//    Stage-write b128 (4 rows x 16 grans) and produce-read b128 (16 rows x 4
//    grans) both touch each 4-bank set exactly 8x per 1KB -> at floor.
//  - Th/Tl [128 g][32 r] bf16 padded to 80B rows (40 u16). 80B stride => base
//    bank g*20 mod 32 walks {0,20,8,28,16,4,24,12} -> write b64 (4 words/bank
//    uniform = 4-cyc floor) and read b128 (8 words/bank uniform = 8-cyc floor).
//    16B alignment preserved (80 = 5*16).
//
// Fragment convention (identical to v1/v2 which passed): lane l supplies
// operand elems j=0..7 at k=(l>>4)*8+j; A row / B col = l&15. A and B share
// the convention so the true HW k-permutation cancels. C/D: col=l&15,
// row=(l>>4)*4+reg (HW-verified m89/m91).

typedef unsigned short u16;
typedef __attribute__((ext_vector_type(8))) short short8;
typedef __attribute__((ext_vector_type(4))) float float4v;

__device__ __forceinline__ uint32_t pk_bf16(float a, float b) {
    // packs bf16(a) in low 16, bf16(b) in high 16 (RNE)
    __hip_bfloat162 h = __float22bfloat162_rn(make_float2(a, b));
    uint32_t u;
    __builtin_memcpy(&u, &h, 4);
    return u;
}

union S8U { short8 s; uint32_t u[4]; };

// split 8 consecutive fp32 into bf16 hi/lo short8 fragments
__device__ __forceinline__ void split8(const float v[8], short8& hi, short8& lo) {
    S8U H, L;
    #pragma unroll
    for (int p = 0; p < 4; ++p) {
        const uint32_t h = pk_bf16(v[2 * p], v[2 * p + 1]);
        H.u[p] = h;
        const float r0 = v[2 * p]     - __uint_as_float(h << 16);
        const float r1 = v[2 * p + 1] - __uint_as_float(h & 0xFFFF0000u);
        L.u[p] = pk_bf16(r0, r1);
    }
    hi = H.s;
    lo = L.s;
}

// ---------------- Kernel 1: weight fragment prep (unchanged, verified) ----
// d_ws layout (u16 units): [0]=W0hi, [16384]=W0lo, [32768]=W1hi, [49152]=W1lo.
// Fragment linear index r = ((ktile*8 + tile)*64 + lane)*8 + j.
// W0 (phase-1 B): value = w0[k][n], n = tile*16 + (l&15)
// W1 (phase-2 A): value = w1[k][m], m = tile*16 + (l&15)   (A = W1^T)
// both with k = ktile*32 + (l>>4)*8 + j.
__global__ void prep_weights(const float* __restrict__ w0,
                             const float* __restrict__ w1,
                             u16* __restrict__ wsp) {
    const int tid = blockIdx.x * 256 + threadIdx.x;  // 0..32767
    const int m  = tid >> 14;                        // 0: w0, 1: w1
    const int r  = tid & 16383;
    const int fi = r >> 9;        // 0..31
    const int l  = (r >> 3) & 63;
    const int j  = r & 7;
    const int ktile = fi >> 3, tile = fi & 7;
    const int k = ktile * 32 + (l >> 4) * 8 + j;
    const int c = tile * 16 + (l & 15);
    const float v = (m ? w1 : w0)[k * 128 + c];

    const uint32_t hu = pk_bf16(v, 0.0f);
    const u16 hb = (u16)(hu & 0xFFFF);
    const float hf = __uint_as_float(hu << 16);
    const u16 lb = (u16)(pk_bf16(v - hf, 0.0f) & 0xFFFF);

    u16* base = wsp + m * 32768;
    base[r] = hb;
    base[16384 + r] = lb;
}

// ---------------- Kernel 2: v3 fused sandwich ----------------
__global__ __launch_bounds__(256, 4) void faclin_v3(
    const float* __restrict__ x,     // (B, 16384) fp32
    const u16* __restrict__ wsp,     // prepped weight frags
    float* __restrict__ out)         // (B, 16384) fp32
{
    __shared__ alignas(16) u16 Xh[32 * 128];   // 8 KB  X chunk hi (swizzled)
    __shared__ alignas(16) u16 Xl[32 * 128];   // 8 KB  X chunk lo
    __shared__ alignas(16) u16 Th[128 * 40];   // 10 KB T chunk hi [g][r], 80B rows
    __shared__ alignas(16) u16 Tl[128 * 40];   // 10 KB T chunk lo

    const int b = blockIdx.x;
    const int t = threadIdx.x;
    const int l = t & 63, w = t >> 6;
    const int l15 = l & 15, lg = l >> 4;
    const float* __restrict__ xb = x + (size_t)b * 16384;
    float* __restrict__ ob = out + (size_t)b * 16384;

    const u16* __restrict__ W0h = wsp;
    const u16* __restrict__ W0l = wsp + 16384;
    const u16* __restrict__ W1h = wsp + 32768;
    const u16* __restrict__ W1l = wsp + 49152;

    // Persistent phase-2 accumulators: wave w owns O rows [32w, 32w+32).
    float4v acc2[2][8];
    #pragma unroll
    for (int i = 0; i < 2; ++i)
        #pragma unroll
        for (int j = 0; j < 8; ++j) acc2[i][j] = {0.f, 0.f, 0.f, 0.f};

    for (int c = 0; c < 4; ++c) {  // T/X row-chunk [32c, 32c+32)
        // ---- Stage X chunk: coalesced, all loads issued before any split ----
        {
            const float4* __restrict__ src = (const float4*)(xb + c * 4096);
            const float4 v0 = src[2 * t];
            const float4 v1 = src[2 * t + 1];
            const float4 v2 = src[512 + 2 * t];
            const float4 v3 = src[512 + 2 * t + 1];
            const int row0 = t >> 4;          // pass0 row (0..15); pass1 = +16
            const int gofs = ((t & 15) ^ row0) * 8;  // swizzled granule, u16 units
            float f[8];
            short8 hi, lo;
            *(float4*)&f[0] = v0; *(float4*)&f[4] = v1;
            split8(f, hi, lo);
            *(short8*)&Xh[row0 * 128 + gofs] = hi;
            *(short8*)&Xl[row0 * 128 + gofs] = lo;
            *(float4*)&f[0] = v2; *(float4*)&f[4] = v3;
            split8(f, hi, lo);
            *(short8*)&Xh[(16 + row0) * 128 + gofs] = hi;  // (16+row0)&15 == row0
            *(short8*)&Xl[(16 + row0) * 128 + gofs] = lo;
        }
        __syncthreads();

        // ---- Produce: T[32c.., 32w + nt*16 + ..] = Xchunk * W0 ----
        float4v accP[2][2];
        #pragma unroll
        for (int i = 0; i < 2; ++i)
            #pragma unroll
            for (int j = 0; j < 2; ++j) accP[i][j] = {0.f, 0.f, 0.f, 0.f};

        #pragma unroll
        for (int kt = 0; kt < 4; ++kt) {
            short8 bh[2], bl[2];
            #pragma unroll
            for (int nt = 0; nt < 2; ++nt) {
                const int off = ((kt * 8 + 2 * w + nt) * 64 + l) * 8;
                bh[nt] = *(const short8*)&W0h[off];
                bl[nt] = *(const short8*)&W0l[off];
            }
            #pragma unroll
            for (int mt = 0; mt < 2; ++mt) {
                const int row  = mt * 16 + l15;                 // chunk-local
                const int gran = (kt * 4 + lg) ^ (row & 15);
                const short8 ah = *(const short8*)&Xh[row * 128 + gran * 8];
                const short8 al = *(const short8*)&Xl[row * 128 + gran * 8];
                #pragma unroll
                for (int nt = 0; nt < 2; ++nt) {
                    accP[mt][nt] = __builtin_amdgcn_mfma_f32_16x16x32_bf16(al, bh[nt], accP[mt][nt], 0, 0, 0);
                    accP[mt][nt] = __builtin_amdgcn_mfma_f32_16x16x32_bf16(ah, bl[nt], accP[mt][nt], 0, 0, 0);
                    accP[mt][nt] = __builtin_amdgcn_mfma_f32_16x16x32_bf16(ah, bh[nt], accP[mt][nt], 0, 0, 0);
                }
            }
        }

        // ---- Write T chunk to LDS: Th/Tl[g][r_local], 80B rows, b64 ----
        // acc reg q: r_local = mt*16 + lg*4 + q, g = 32w + nt*16 + l15.
        #pragma unroll
        for (int mt = 0; mt < 2; ++mt)
            #pragma unroll
            for (int nt = 0; nt < 2; ++nt) {
                const int g   = 32 * w + nt * 16 + l15;
                const int r0  = mt * 16 + lg * 4;
                const int idx = g * 40 + r0;     // u16 units (40 u16 = 80B row)
                const float4v a = accP[mt][nt];
                const uint32_t h01 = pk_bf16(a[0], a[1]);
                const uint32_t h23 = pk_bf16(a[2], a[3]);
                const float f0 = __uint_as_float(h01 << 16);
                const float f1 = __uint_as_float(h01 & 0xFFFF0000u);
                const float f2 = __uint_as_float(h23 << 16);
                const float f3 = __uint_as_float(h23 & 0xFFFF0000u);
                const uint32_t l01 = pk_bf16(a[0] - f0, a[1] - f1);
                const uint32_t l23 = pk_bf16(a[2] - f2, a[3] - f3);
                *(uint64_t*)&Th[idx] = (uint64_t)h01 | ((uint64_t)h23 << 32);
                *(uint64_t*)&Tl[idx] = (uint64_t)l01 | ((uint64_t)l23 << 32);
            }
        __syncthreads();

        // ---- Consume: O[32w..][:] += W1^T[:, 32c..] * Tchunk (K=32 step) ----
        short8 a2h[2], a2l[2];
        #pragma unroll
        for (int mt = 0; mt < 2; ++mt) {
            const int off = ((c * 8 + 2 * w + mt) * 64 + l) * 8;
            a2h[mt] = *(const short8*)&W1h[off];
            a2l[mt] = *(const short8*)&W1l[off];
        }
        #pragma unroll
        for (int nt = 0; nt < 8; ++nt) {
            const int g   = nt * 16 + l15;
            const int idx = g * 40 + lg * 8;     // b128: r_local = lg*8 .. +7
            const short8 bh = *(const short8*)&Th[idx];
            const short8 bl = *(const short8*)&Tl[idx];
            #pragma unroll
            for (int mt = 0; mt < 2; ++mt) {
                acc2[mt][nt] = __builtin_amdgcn_mfma_f32_16x16x32_bf16(a2l[mt], bh, acc2[mt][nt], 0, 0, 0);
                acc2[mt][nt] = __builtin_amdgcn_mfma_f32_16x16x32_bf16(a2h[mt], bl, acc2[mt][nt], 0, 0, 0);
                acc2[mt][nt] = __builtin_amdgcn_mfma_f32_16x16x32_bf16(a2h[mt], bh, acc2[mt][nt], 0, 0, 0);
            }
        }
        __syncthreads();  // T consumed + Xs reads done before next chunk writes
    }

    // ---- Store O. C/D: row = lg*4 + q, col = l15 per 16x16 tile. ----
    #pragma unroll
    for (int mt = 0; mt < 2; ++mt)
        #pragma unroll
        for (int nt = 0; nt < 8; ++nt)
            #pragma unroll
            for (int q = 0; q < 4; ++q) {
                const int orow = 32 * w + mt * 16 + lg * 4 + q;
                const int ocol = nt * 16 + l15;
                ob[(size_t)orow * 128 + ocol] = acc2[mt][nt][q];
            }
}

extern "C" void kernel_launch(void* const* d_in, const int* in_sizes, int n_in,
                              void* d_out, int out_size, void* d_ws, size_t ws_size,
                              hipStream_t stream) {
    const float* x  = (const float*)d_in[0];
    const float* w0 = (const float*)d_in[1];
    const float* w1 = (const float*)d_in[2];
    float* out = (float*)d_out;
    u16* wsp = (u16*)d_ws;  // 128 KB of scratch used

    const int B = in_sizes[0] >> 14;  // 4096

    prep_weights<<<128, 256, 0, stream>>>(w0, w1, wsp);
    faclin_v3<<<B, 256, 0, stream>>>(x, (const u16*)wsp, out);
}

// Round 10
// 566.718 us; speedup vs baseline: 1.1156x; 1.0449x over previous
//
#include <hip/hip_runtime.h>
#include <hip/hip_bf16.h>
#include <stdint.h>

// Fused Kronecker-factorized linear via bf16-split MFMA (3-product fp32 emulation):
//   out[b, 128*gp + g] = sum_{r,f} x[b, 128*r + f] * w0[f][g] * w1[r][gp]
//   (per batch: Out = W1^T * X * W0, all 128x128)
//
// v4 = v3 + full-line O-store epilogue (single change, for attribution).
// v3 post-mortem: scalar 4B O-stores wrote disjoint 64B half-lines; with ~8MB
// dirty O per 4MB XCD-L2, half-written lines evicted -> RFO re-fetch + double
// write (WRITE 513MB = 2x ideal, FETCH 612MB = X + O-RFO). v1's float4 stores
// had exact 262MB WRITE. Fix: stage O through per-wave-private LDS (T buffers
// are dead after the last consume barrier; no cross-wave sharing -> no extra
// barriers), store float4 = 1024B contiguous per instruction = full lines.
//
// Structure (unchanged from v3):
//  - T rows [32c,32c+32) need only X rows [32c,32c+32): stream both through
//    small LDS chunks; per chunk: coalesced float4 X load -> bf16 hi/lo LDS
//    -> produce T (MFMA) -> T hi/lo LDS (80B rows) -> consume K=32 step into
//    persistent O accumulators.
//  - LDS 36KB, launch_bounds(256,4) -> 4 blocks/CU = 16 waves/CU.
//
// Bank math: X granule-XOR and T 80B-row layouts at per-instruction floors
// (see v3 notes). Epilogue patch [16][132] floats per wave: write side 2-way
// (free), read side uniform 8 words/bank (floor).
//
// Fragment convention (identical to v1/v2/v3, twice HW-validated): lane l
// supplies operand elems j=0..7 at k=(l>>4)*8+j; A row / B col = l&15.
// C/D: col=l&15, row=(l>>4)*4+reg (HW-verified m89/m91).

typedef unsigned short u16;
typedef __attribute__((ext_vector_type(8))) short short8;
typedef __attribute__((ext_vector_type(4))) float float4v;

__device__ __forceinline__ uint32_t pk_bf16(float a, float b) {
    // packs bf16(a) in low 16, bf16(b) in high 16 (RNE)
    __hip_bfloat162 h = __float22bfloat162_rn(make_float2(a, b));
    uint32_t u;
    __builtin_memcpy(&u, &h, 4);
    return u;
}

union S8U { short8 s; uint32_t u[4]; };

// split 8 consecutive fp32 into bf16 hi/lo short8 fragments
__device__ __forceinline__ void split8(const float v[8], short8& hi, short8& lo) {
    S8U H, L;
    #pragma unroll
    for (int p = 0; p < 4; ++p) {
        const uint32_t h = pk_bf16(v[2 * p], v[2 * p + 1]);
        H.u[p] = h;
        const float r0 = v[2 * p]     - __uint_as_float(h << 16);
        const float r1 = v[2 * p + 1] - __uint_as_float(h & 0xFFFF0000u);
        L.u[p] = pk_bf16(r0, r1);
    }
    hi = H.s;
    lo = L.s;
}

// ---------------- Kernel 1: weight fragment prep (unchanged, verified) ----
// d_ws layout (u16 units): [0]=W0hi, [16384]=W0lo, [32768]=W1hi, [49152]=W1lo.
// Fragment linear index r = ((ktile*8 + tile)*64 + lane)*8 + j.
// W0 (phase-1 B): value = w0[k][n], n = tile*16 + (l&15)
// W1 (phase-2 A): value = w1[k][m], m = tile*16 + (l&15)   (A = W1^T)
// both with k = ktile*32 + (l>>4)*8 + j.
__global__ void prep_weights(const float* __restrict__ w0,
                             const float* __restrict__ w1,
                             u16* __restrict__ wsp) {
    const int tid = blockIdx.x * 256 + threadIdx.x;  // 0..32767
    const int m  = tid >> 14;                        // 0: w0, 1: w1
    const int r  = tid & 16383;
    const int fi = r >> 9;        // 0..31
    const int l  = (r >> 3) & 63;
    const int j  = r & 7;
    const int ktile = fi >> 3, tile = fi & 7;
    const int k = ktile * 32 + (l >> 4) * 8 + j;
    const int c = tile * 16 + (l & 15);
    const float v = (m ? w1 : w0)[k * 128 + c];

    const uint32_t hu = pk_bf16(v, 0.0f);
    const u16 hb = (u16)(hu & 0xFFFF);
    const float hf = __uint_as_float(hu << 16);
    const u16 lb = (u16)(pk_bf16(v - hf, 0.0f) & 0xFFFF);

    u16* base = wsp + m * 32768;
    base[r] = hb;
    base[16384 + r] = lb;
}

// ---------------- Kernel 2: v4 fused sandwich ----------------
__global__ __launch_bounds__(256, 4) void faclin_v4(
    const float* __restrict__ x,     // (B, 16384) fp32
    const u16* __restrict__ wsp,     // prepped weight frags
    float* __restrict__ out)         // (B, 16384) fp32
{
    // 36 KB shared pool, carved: Xh(4096 u16) Xl(4096) Th(5120) Tl(5120).
    // Reused as float[9216] by the epilogue (per-wave patches of 2112 floats).
    __shared__ alignas(16) u16 S[18432];
    u16* const Xh = S;              // [32 r][128 f] bf16 hi, granule-XOR swizzled
    u16* const Xl = S + 4096;
    u16* const Th = S + 8192;       // [128 g][40] bf16 hi, 80B rows (32 used)
    u16* const Tl = S + 13312;

    const int b = blockIdx.x;
    const int t = threadIdx.x;
    const int l = t & 63, w = t >> 6;
    const int l15 = l & 15, lg = l >> 4;
    const float* __restrict__ xb = x + (size_t)b * 16384;
    float* __restrict__ ob = out + (size_t)b * 16384;

    const u16* __restrict__ W0h = wsp;
    const u16* __restrict__ W0l = wsp + 16384;
    const u16* __restrict__ W1h = wsp + 32768;
    const u16* __restrict__ W1l = wsp + 49152;

    // Persistent phase-2 accumulators: wave w owns O rows [32w, 32w+32).
    float4v acc2[2][8];
    #pragma unroll
    for (int i = 0; i < 2; ++i)
        #pragma unroll
        for (int j = 0; j < 8; ++j) acc2[i][j] = {0.f, 0.f, 0.f, 0.f};

    for (int c = 0; c < 4; ++c) {  // T/X row-chunk [32c, 32c+32)
        // ---- Stage X chunk: coalesced, all loads issued before any split ----
        {
            const float4* __restrict__ src = (const float4*)(xb + c * 4096);
            const float4 v0 = src[2 * t];
            const float4 v1 = src[2 * t + 1];
            const float4 v2 = src[512 + 2 * t];
            const float4 v3 = src[512 + 2 * t + 1];
            const int row0 = t >> 4;          // pass0 row (0..15); pass1 = +16
            const int gofs = ((t & 15) ^ row0) * 8;  // swizzled granule, u16 units
            float f[8];
            short8 hi, lo;
            *(float4*)&f[0] = v0; *(float4*)&f[4] = v1;
            split8(f, hi, lo);
            *(short8*)&Xh[row0 * 128 + gofs] = hi;
            *(short8*)&Xl[row0 * 128 + gofs] = lo;
            *(float4*)&f[0] = v2; *(float4*)&f[4] = v3;
            split8(f, hi, lo);
            *(short8*)&Xh[(16 + row0) * 128 + gofs] = hi;  // (16+row0)&15 == row0
            *(short8*)&Xl[(16 + row0) * 128 + gofs] = lo;
        }
        __syncthreads();

        // ---- Produce: T[32c.., 32w + nt*16 + ..] = Xchunk * W0 ----
        float4v accP[2][2];
        #pragma unroll
        for (int i = 0; i < 2; ++i)
            #pragma unroll
            for (int j = 0; j < 2; ++j) accP[i][j] = {0.f, 0.f, 0.f, 0.f};

        #pragma unroll
        for (int kt = 0; kt < 4; ++kt) {
            short8 bh[2], bl[2];
            #pragma unroll
            for (int nt = 0; nt < 2; ++nt) {
                const int off = ((kt * 8 + 2 * w + nt) * 64 + l) * 8;
                bh[nt] = *(const short8*)&W0h[off];
                bl[nt] = *(const short8*)&W0l[off];
            }
            #pragma unroll
            for (int mt = 0; mt < 2; ++mt) {
                const int row  = mt * 16 + l15;                 // chunk-local
                const int gran = (kt * 4 + lg) ^ (row & 15);
                const short8 ah = *(const short8*)&Xh[row * 128 + gran * 8];
                const short8 al = *(const short8*)&Xl[row * 128 + gran * 8];
                #pragma unroll
                for (int nt = 0; nt < 2; ++nt) {
                    accP[mt][nt] = __builtin_amdgcn_mfma_f32_16x16x32_bf16(al, bh[nt], accP[mt][nt], 0, 0, 0);
                    accP[mt][nt] = __builtin_amdgcn_mfma_f32_16x16x32_bf16(ah, bl[nt], accP[mt][nt], 0, 0, 0);
                    accP[mt][nt] = __builtin_amdgcn_mfma_f32_16x16x32_bf16(ah, bh[nt], accP[mt][nt], 0, 0, 0);
                }
            }
        }

        // ---- Write T chunk to LDS: Th/Tl[g][r_local], 80B rows, b64 ----
        // acc reg q: r_local = mt*16 + lg*4 + q, g = 32w + nt*16 + l15.
        #pragma unroll
        for (int mt = 0; mt < 2; ++mt)
            #pragma unroll
            for (int nt = 0; nt < 2; ++nt) {
                const int g   = 32 * w + nt * 16 + l15;
                const int r0  = mt * 16 + lg * 4;
                const int idx = g * 40 + r0;     // u16 units (40 u16 = 80B row)
                const float4v a = accP[mt][nt];
                const uint32_t h01 = pk_bf16(a[0], a[1]);
                const uint32_t h23 = pk_bf16(a[2], a[3]);
                const float f0 = __uint_as_float(h01 << 16);
                const float f1 = __uint_as_float(h01 & 0xFFFF0000u);
                const float f2 = __uint_as_float(h23 << 16);
                const float f3 = __uint_as_float(h23 & 0xFFFF0000u);
                const uint32_t l01 = pk_bf16(a[0] - f0, a[1] - f1);
                const uint32_t l23 = pk_bf16(a[2] - f2, a[3] - f3);
                *(uint64_t*)&Th[idx] = (uint64_t)h01 | ((uint64_t)h23 << 32);
                *(uint64_t*)&Tl[idx] = (uint64_t)l01 | ((uint64_t)l23 << 32);
            }
        __syncthreads();

        // ---- Consume: O[32w..][:] += W1^T[:, 32c..] * Tchunk (K=32 step) ----
        short8 a2h[2], a2l[2];
        #pragma unroll
        for (int mt = 0; mt < 2; ++mt) {
            const int off = ((c * 8 + 2 * w + mt) * 64 + l) * 8;
            a2h[mt] = *(const short8*)&W1h[off];
            a2l[mt] = *(const short8*)&W1l[off];
        }
        #pragma unroll
        for (int nt = 0; nt < 8; ++nt) {
            const int g   = nt * 16 + l15;
            const int idx = g * 40 + lg * 8;     // b128: r_local = lg*8 .. +7
            const short8 bh = *(const short8*)&Th[idx];
            const short8 bl = *(const short8*)&Tl[idx];
            #pragma unroll
            for (int mt = 0; mt < 2; ++mt) {
                acc2[mt][nt] = __builtin_amdgcn_mfma_f32_16x16x32_bf16(a2l[mt], bh, acc2[mt][nt], 0, 0, 0);
                acc2[mt][nt] = __builtin_amdgcn_mfma_f32_16x16x32_bf16(a2h[mt], bl, acc2[mt][nt], 0, 0, 0);
                acc2[mt][nt] = __builtin_amdgcn_mfma_f32_16x16x32_bf16(a2h[mt], bh, acc2[mt][nt], 0, 0, 0);
            }
        }
        __syncthreads();  // T consumed before next chunk / before epilogue reuse
    }

    // ---- Epilogue: per-wave LDS transpose -> full-line float4 stores ----
    // LDS is dead (last barrier passed). Each wave uses a PRIVATE patch of
    // [16][132] floats (132 = +4 pad; rows q vs q+8 2-way = free), so no
    // barriers are needed. Two rounds (mt=0: rows 32w..+15, mt=1: +16..31).
    // Store instr i covers rows {2i,2i+1} x 128 cols = 1024B contiguous.
    {
        float* const P = (float*)S + w * 2112;   // 2112 = 16*132
        #pragma unroll
        for (int mt = 0; mt < 2; ++mt) {
            #pragma unroll
            for (int nt = 0; nt < 8; ++nt)
                #pragma unroll
                for (int q = 0; q < 4; ++q)
                    P[(lg * 4 + q) * 132 + nt * 16 + l15] = acc2[mt][nt][q];
            // wave-private: compiler's lgkmcnt ordering suffices, no barrier
            #pragma unroll
            for (int i = 0; i < 8; ++i) {
                const int rr = 2 * i + (l >> 5);
                const int cc = (l & 31) * 4;
                const float4 v = *(const float4*)&P[rr * 132 + cc];
                *(float4*)&ob[(size_t)(32 * w + mt * 16 + rr) * 128 + cc] = v;
            }
        }
    }
}

extern "C" void kernel_launch(void* const* d_in, const int* in_sizes, int n_in,
                              void* d_out, int out_size, void* d_ws, size_t ws_size,
                              hipStream_t stream) {
    const float* x  = (const float*)d_in[0];
    const float* w0 = (const float*)d_in[1];
    const float* w1 = (const float*)d_in[2];
    float* out = (float*)d_out;
    u16* wsp = (u16*)d_ws;  // 128 KB of scratch used

    const int B = in_sizes[0] >> 14;  // 4096

    prep_weights<<<128, 256, 0, stream>>>(w0, w1, wsp);
    faclin_v4<<<B, 256, 0, stream>>>(x, (const u16*)wsp, out);
}